// Round 11
// baseline (5915.301 us; speedup 1.0000x reference)
//
#include <hip/hip_runtime.h>
#include <math.h>

typedef unsigned short u16;
typedef __attribute__((ext_vector_type(8))) short bf16x8;   // MFMA A/B frag
typedef __attribute__((ext_vector_type(4))) float f32x4;    // MFMA C/D frag

#define T_STEPS 32
#define BSZ     32
#define N_IN    64
#define H       256
#define N_OUT   64
#define ESTRIDE 9984              // rows = 320*31 + 64
#define CLAMP_MIN (-2.0f)
#define CLAMP_MAX ( 2.0f)
#define NSLOT   16                // blocks per sample (grid 16 x 32 = 512 = 2/CU)

// Fragment-packed layout: chunk = (row>>4)*8 + (k>>5), 512 u16/chunk,
// within-chunk elem = (((k&31)>>3)*16 + (row&15))*8 + (k&7).

__device__ inline u16 f2bf(float x) {                       // RTNE fp32->bf16
    unsigned u = __builtin_bit_cast(unsigned, x);
    unsigned r = u + 0x7FFFu + ((u >> 16) & 1u);
    return (u16)(r >> 16);
}

// ---------------------------------------------------------------------------
__global__ void init_k(float* __restrict__ p) {             // zero radT+rad_o+cnt
    p[blockIdx.x * 256 + threadIdx.x] = 0.0f;
}

// ---------------------------------------------------------------------------
// Frag-ordered fp32 weights: Wf[((nf*8+kc)*64+lane)*8+j] = W[(kc*32+(lane>>4)*8+j)*ns + nf*16+(lane&15)]
// ---------------------------------------------------------------------------
__global__ void packWf_k(const float* __restrict__ W, float* __restrict__ Wf,
                         int NF, int ns)
{
    int g = blockIdx.x * 256 + threadIdx.x;
    if (g >= NF * 8 * 64) return;
    int lane = g & 63, kc = (g >> 6) & 7;
    int m = lane & 15, q = lane >> 4;
    int nf = g >> 9;
    float* dst = Wf + (size_t)g * 8;
    #pragma unroll
    for (int j = 0; j < 8; ++j)
        dst[j] = W[(size_t)(kc * 32 + q * 8 + j) * ns + nf * 16 + m];
}

// ---------------------------------------------------------------------------
// prep0: hp[0], rad[0], fresh rows [0,64); then mid(1): tanh -> WTp(parity 1),
// diag rows [64,320), fresh [320,384) from X[1], hp[1], rad[1] init.
// grid BSZ x 256 (one block per sample; all in-block deps).
// ---------------------------------------------------------------------------
__global__ __launch_bounds__(256) void prep0_k(
    const float* __restrict__ X, const float* __restrict__ eps,
    const float* __restrict__ Wih, const float* __restrict__ Whh,
    const float* __restrict__ WhhTf,
    const float* __restrict__ bih, const float* __restrict__ bhh,
    float* __restrict__ hp, float* __restrict__ radT,
    u16* __restrict__ err, u16* __restrict__ WTp)
{
    __shared__ float hx[N_IN], rr[N_IN], acc_s[H];
    __shared__ float lam_s[H], de_s[H], hh_s[H];
    const int b = blockIdx.x, tid = threadIdx.x;
    const int lane = tid & 63, w4 = tid >> 6;
    const int e = tid * 2, qe = e >> 7, me = (e >> 3) & 15, je = e & 7;
    u16* errB = err + (size_t)b * ESTRIDE * H;
    const float ebs = eps[b];

    if (tid < N_IN) {
        float x = X[b * N_IN + tid];
        float l = fmaxf(x - ebs, CLAMP_MIN), u = fminf(x + ebs, CLAMP_MAX);
        hx[tid] = 0.5f * (l + u);
        rr[tid] = 0.5f * (u - l);
    }
    acc_s[tid] = 0.f;
    __syncthreads();

    float hp0 = bih[tid] + bhh[tid];
    #pragma unroll 8
    for (int i = 0; i < N_IN; ++i) hp0 += hx[i] * Wih[i * H + tid];
    hp[b * H + tid] = hp0;                                  // hp[0], parity 0

    // fresh rows [0,64)
    #pragma unroll
    for (int ti = 0; ti < 4; ++ti) {
        int i = ti * 16 + me;
        float rho = rr[i];
        const float* wrow = Wih + (size_t)i * H;
        #pragma unroll
        for (int kc = 0; kc < 8; ++kc) {
            int k = kc * 32 + qe * 8 + je;
            float v0 = rho * wrow[k], v1 = rho * wrow[k + 1];
            unsigned pk = (unsigned)f2bf(v0) | ((unsigned)f2bf(v1) << 16);
            *(unsigned*)&errB[(size_t)(ti * 8 + kc) * 512 + e] = pk;
            atomicAdd(&acc_s[k], fabsf(v0));
            atomicAdd(&acc_s[k + 1], fabsf(v1));
        }
    }
    __syncthreads();
    float rad0 = acc_s[tid];
    atomicAdd(&radT[b * H + tid], rad0);                    // radT[0]

    // ---- mid(1): tanh of (hp0, rad0) ----
    {
        float l = hp0 - rad0, u = hp0 + rad0;
        float tl = tanhf(l), tu = tanhf(u);
        float la = fminf(1.f - tl * tl, 1.f - tu * tu);
        float mu = 0.5f * (tu + tl - la * (u + l));
        float dd = 0.5f * (tu - tl - la * (u - l));
        lam_s[tid] = la; de_s[tid] = dd; hh_s[tid] = la * hp0 + mu;
    }
    if (tid < N_IN) {                                       // X[1] mids
        float x = X[(size_t)(BSZ + b) * N_IN + tid];
        float lo = fmaxf(x - ebs, CLAMP_MIN), up = fminf(x + ebs, CLAMP_MAX);
        hx[tid] = 0.5f * (lo + up);
        rr[tid] = 0.5f * (up - lo);
    }
    acc_s[tid] = 0.f;
    __syncthreads();

    // WTp parity 1 (all 16 nf)
    {
        u16* WTb = WTp + ((size_t)1 * BSZ + b) * H * H;
        for (int nf = 0; nf < 16; ++nf) {
            #pragma unroll
            for (int k2 = 0; k2 < 2; ++k2) {
                int kc = w4 * 2 + k2;
                const float* src = WhhTf + (size_t)((nf * 8 + kc) * 64 + lane) * 8;
                int k0 = kc * 32 + (lane >> 4) * 8;
                union { u16 us[8]; uint4 v; } pk;
                #pragma unroll
                for (int j = 0; j < 8; ++j) pk.us[j] = f2bf(lam_s[k0 + j] * src[j]);
                *(uint4*)&WTp[((size_t)1 * BSZ + b) * H * H + (size_t)(nf * 8 + kc) * 512 + lane * 8] = pk.v;
            }
        }
        (void)WTb;
    }
    // diag rows [64, 320)
    for (int r = 0; r < 4; ++r) {
        #pragma unroll
        for (int ti = 0; ti < 4; ++ti) {
            int rsrc = r * 64 + ti * 16 + me;
            float dv = de_s[rsrc];
            const float* wrow = Whh + (size_t)rsrc * H;
            #pragma unroll
            for (int kc = 0; kc < 8; ++kc) {
                int k = kc * 32 + qe * 8 + je;
                float v0 = dv * wrow[k], v1 = dv * wrow[k + 1];
                unsigned pv = (unsigned)f2bf(v0) | ((unsigned)f2bf(v1) << 16);
                *(unsigned*)&errB[(size_t)((4 + r * 4 + ti) * 8 + kc) * 512 + e] = pv;
                atomicAdd(&acc_s[k], fabsf(v0));
                atomicAdd(&acc_s[k + 1], fabsf(v1));
            }
        }
    }
    // fresh rows [320, 384) from X[1]
    #pragma unroll
    for (int ti = 0; ti < 4; ++ti) {
        int i = ti * 16 + me;
        float rho = rr[i];
        const float* wrow = Wih + (size_t)i * H;
        #pragma unroll
        for (int kc = 0; kc < 8; ++kc) {
            int k = kc * 32 + qe * 8 + je;
            float v0 = rho * wrow[k], v1 = rho * wrow[k + 1];
            unsigned pv = (unsigned)f2bf(v0) | ((unsigned)f2bf(v1) << 16);
            *(unsigned*)&errB[(size_t)((20 + ti) * 8 + kc) * 512 + e] = pv;
            atomicAdd(&acc_s[k], fabsf(v0));
            atomicAdd(&acc_s[k + 1], fabsf(v1));
        }
    }
    // head GEMV -> hp[1] (parity 1)
    float acc2 = bih[tid] + bhh[tid];
    #pragma unroll 8
    for (int i = 0; i < N_IN; ++i) acc2 += hx[i] * Wih[i * H + tid];
    #pragma unroll 8
    for (int j = 0; j < H; ++j) acc2 += hh_s[j] * Whh[j * H + tid];
    hp[(size_t)BSZ * H + b * H + tid] = acc2;
    __syncthreads();
    atomicAdd(&radT[(size_t)BSZ * H + b * H + tid], acc_s[tid]);   // radT[1]
}

// ---------------------------------------------------------------------------
// step_k (t=1..31), ONE dispatch per step:
//  phase 1: r7-verbatim gemm over [0, 320t-256) with B from WTp[t&1]
//  handshake: radT[t] atomics -> fence -> per-sample counter; spin till 16
//  phase 2 (mid for t+1, partitioned by slot):
//    0-7: WTp[1-(t&1)] slices   8-11: diag quarters   12: fresh (no spin)
//    13: head GEMV -> hp[t+1]   (t==31: 0-3 WoTp, 4 head_o+diag-rad)
// ---------------------------------------------------------------------------
__global__ __launch_bounds__(256, 2) void step_k(
    const float* __restrict__ X, const float* __restrict__ eps,
    const float* __restrict__ Wih, const float* __restrict__ Whh,
    const float* __restrict__ WhhTf, const float* __restrict__ WoTf,
    const float* __restrict__ Wo, const float* __restrict__ bo_v,
    const float* __restrict__ bih, const float* __restrict__ bhh,
    float* __restrict__ hp, float* __restrict__ radT,
    u16* __restrict__ err, u16* __restrict__ WTp, u16* __restrict__ WoTp,
    float* __restrict__ head_o, float* __restrict__ rad_o,
    int* __restrict__ cnt, int t)
{
    __shared__ u16 tbuf[4][4096];          // 32 KB transform buffer
    __shared__ float lam_s[H], de_s[H], hh_s[H], radacc[H];
    __shared__ float hxm[N_IN], hxr[N_IN];
    const int slot = blockIdx.x, b = blockIdx.y, tid = threadIdx.x;
    const int wave = tid >> 6, lane = tid & 63;
    const int m = lane & 15, q = lane >> 4;
    const int e = tid * 2, qe = e >> 7, me = (e >> 3) & 15, je = e & 7;
    const int ntiles = (320 * t - 256) >> 6;
    const int pr = t & 1;
    u16* errB = err + (size_t)b * ESTRIDE * H;
    float* rad_t  = radT + (size_t)t * BSZ * H;

    radacc[tid] = 0.f;
    const bool hasg = (slot < ntiles);
    bf16x8 bfr[4][8];
    if (hasg) {
        const u16* WTb = WTp + ((size_t)pr * BSZ + b) * H * H;
        #pragma unroll
        for (int nt = 0; nt < 4; ++nt)
            #pragma unroll
            for (int kc = 0; kc < 8; ++kc)
                bfr[nt][kc] = *(const bf16x8*)&WTb[(size_t)((wave * 4 + nt) * 8 + kc) * 512 + lane * 8];
    }
    __syncthreads();

    for (int tau = slot; tau < ntiles; tau += NSLOT) {
        const int tile = tau;
        f32x4 acc[4][4];
        #pragma unroll
        for (int i = 0; i < 4; ++i)
            #pragma unroll
            for (int c = 0; c < 4; ++c) acc[i][c] = (f32x4){0.f, 0.f, 0.f, 0.f};
        #pragma unroll
        for (int kc = 0; kc < 8; ++kc) {
            bf16x8 af[4];
            #pragma unroll
            for (int rt = 0; rt < 4; ++rt)
                af[rt] = *(const bf16x8*)&errB[(size_t)((tile * 4 + rt) * 8 + kc) * 512 + lane * 8];
            #pragma unroll
            for (int nt = 0; nt < 4; ++nt)
                #pragma unroll
                for (int rt = 0; rt < 4; ++rt)
                    acc[rt][nt] = __builtin_amdgcn_mfma_f32_16x16x32_bf16(
                        af[rt], bfr[nt][kc], acc[rt][nt], 0, 0, 0);
        }
        __syncthreads();   // all waves consumed A before in-place stores
        u16* W_ = tbuf[wave];
        #pragma unroll
        for (int nt = 0; nt < 4; ++nt) {
            int c32 = (nt & 1) * 16 + m;
            int q_a = c32 >> 3, jj = c32 & 7, kcl = nt >> 1;
            float s = 0.f;
            #pragma unroll
            for (int rt = 0; rt < 4; ++rt)
                #pragma unroll
                for (int r = 0; r < 4; ++r) {
                    float v = acc[rt][nt][r];
                    s += fabsf(v);
                    W_[rt * 1024 + kcl * 512 + (q_a * 16 + q * 4 + r) * 8 + jj] = f2bf(v);
                }
            atomicAdd(&radacc[wave * 64 + nt * 16 + m], s);
        }
        #pragma unroll
        for (int rt = 0; rt < 4; ++rt)
            #pragma unroll
            for (int kcl = 0; kcl < 2; ++kcl) {
                uint4 v = *(uint4*)&W_[rt * 1024 + kcl * 512 + lane * 8];
                *(uint4*)&errB[(size_t)((tile * 4 + rt) * 8 + wave * 2 + kcl) * 512 + lane * 8] = v;
            }
    }
    __syncthreads();
    atomicAdd(&rad_t[b * H + tid], radacc[tid]);
    __threadfence();
    if (tid == 0)
        __hip_atomic_fetch_add(&cnt[t * BSZ + b], 1, __ATOMIC_RELEASE,
                               __HIP_MEMORY_SCOPE_AGENT);

    const float ebs = eps[b];
    if (t < 31) {
        if (slot > 13) return;
        float* rad_t1 = radT + (size_t)(t + 1) * BSZ * H;
        if (slot == 12) {                   // fresh rows: no tanh dependency
            const int E1 = 320 * (t + 1);
            if (tid < N_IN) {
                float x = X[(size_t)((t + 1) * BSZ + b) * N_IN + tid];
                float lo = fmaxf(x - ebs, CLAMP_MIN), up = fminf(x + ebs, CLAMP_MAX);
                hxr[tid] = 0.5f * (up - lo);
            }
            radacc[tid] = 0.f;
            __syncthreads();
            #pragma unroll
            for (int ti = 0; ti < 4; ++ti) {
                int i = ti * 16 + me;
                float rho = hxr[i];
                const float* wrow = Wih + (size_t)i * H;
                #pragma unroll
                for (int kc = 0; kc < 8; ++kc) {
                    int k = kc * 32 + qe * 8 + je;
                    float v0 = rho * wrow[k], v1 = rho * wrow[k + 1];
                    unsigned pv = (unsigned)f2bf(v0) | ((unsigned)f2bf(v1) << 16);
                    *(unsigned*)&errB[(size_t)(((E1 >> 4) + ti) * 8 + kc) * 512 + e] = pv;
                    atomicAdd(&radacc[k], fabsf(v0));
                    atomicAdd(&radacc[k + 1], fabsf(v1));
                }
            }
            __syncthreads();
            atomicAdd(&rad_t1[b * H + tid], radacc[tid]);
            return;
        }
        // spin until all 16 blocks of this sample flushed radT[t]
        if (tid == 0)
            while (__hip_atomic_load(&cnt[t * BSZ + b], __ATOMIC_ACQUIRE,
                                     __HIP_MEMORY_SCOPE_AGENT) < NSLOT) {}
        __syncthreads();
        {   // tanh (redundant per block)
            float hd = hp[(size_t)pr * BSZ * H + b * H + tid];
            float r  = __hip_atomic_load(&rad_t[b * H + tid], __ATOMIC_RELAXED,
                                         __HIP_MEMORY_SCOPE_AGENT);
            float l = hd - r, u2 = hd + r;
            float tl = tanhf(l), tu = tanhf(u2);
            float la = fminf(1.f - tl * tl, 1.f - tu * tu);
            float mu = 0.5f * (tu + tl - la * (u2 + l));
            float dd = 0.5f * (tu - tl - la * (u2 - l));
            lam_s[tid] = la; de_s[tid] = dd; hh_s[tid] = la * hd + mu;
        }
        if (slot == 13 && tid < N_IN) {
            float x = X[(size_t)((t + 1) * BSZ + b) * N_IN + tid];
            float lo = fmaxf(x - ebs, CLAMP_MIN), up = fminf(x + ebs, CLAMP_MAX);
            hxm[tid] = 0.5f * (lo + up);
        }
        radacc[tid] = 0.f;
        __syncthreads();

        if (slot < 8) {                     // WTp slices, parity 1-pr
            u16* WTb = WTp + ((size_t)(1 - pr) * BSZ + b) * H * H;
            const int w4 = tid >> 6;
            #pragma unroll
            for (int i2 = 0; i2 < 2; ++i2) {
                int nf = 2 * slot + i2;
                #pragma unroll
                for (int k2 = 0; k2 < 2; ++k2) {
                    int kc = w4 * 2 + k2;
                    const float* src = WhhTf + (size_t)((nf * 8 + kc) * 64 + lane) * 8;
                    int k0 = kc * 32 + (lane >> 4) * 8;
                    union { u16 us[8]; uint4 v; } pk;
                    #pragma unroll
                    for (int j = 0; j < 8; ++j) pk.us[j] = f2bf(lam_s[k0 + j] * src[j]);
                    *(uint4*)&WTb[(size_t)(nf * 8 + kc) * 512 + lane * 8] = pk.v;
                }
            }
        } else if (slot < 12) {             // diag quarters
            const int E1 = 320 * (t + 1), dlo1 = E1 - H;
            const int r = slot - 8;
            #pragma unroll
            for (int ti = 0; ti < 4; ++ti) {
                int rsrc = r * 64 + ti * 16 + me;
                float dv = de_s[rsrc];
                const float* wrow = Whh + (size_t)rsrc * H;
                #pragma unroll
                for (int kc = 0; kc < 8; ++kc) {
                    int k = kc * 32 + qe * 8 + je;
                    float v0 = dv * wrow[k], v1 = dv * wrow[k + 1];
                    unsigned pv = (unsigned)f2bf(v0) | ((unsigned)f2bf(v1) << 16);
                    *(unsigned*)&errB[(size_t)(((dlo1 >> 4) + r * 4 + ti) * 8 + kc) * 512 + e] = pv;
                    atomicAdd(&radacc[k], fabsf(v0));
                    atomicAdd(&radacc[k + 1], fabsf(v1));
                }
            }
            __syncthreads();
            atomicAdd(&rad_t1[b * H + tid], radacc[tid]);
        } else {                            // slot 13: head GEMV -> hp[t+1]
            float acc2 = bih[tid] + bhh[tid];
            #pragma unroll 8
            for (int i = 0; i < N_IN; ++i) acc2 += hxm[i] * Wih[i * H + tid];
            #pragma unroll 8
            for (int j = 0; j < H; ++j) acc2 += hh_s[j] * Whh[j * H + tid];
            hp[(size_t)(1 - pr) * BSZ * H + b * H + tid] = acc2;
        }
    } else {                                // t == 31: final prep
        if (slot > 4) return;
        if (tid == 0)
            while (__hip_atomic_load(&cnt[t * BSZ + b], __ATOMIC_ACQUIRE,
                                     __HIP_MEMORY_SCOPE_AGENT) < NSLOT) {}
        __syncthreads();
        {
            float hd = hp[(size_t)pr * BSZ * H + b * H + tid];
            float r  = __hip_atomic_load(&rad_t[b * H + tid], __ATOMIC_RELAXED,
                                         __HIP_MEMORY_SCOPE_AGENT);
            float l = hd - r, u2 = hd + r;
            float tl = tanhf(l), tu = tanhf(u2);
            float la = fminf(1.f - tl * tl, 1.f - tu * tu);
            float mu = 0.5f * (tu + tl - la * (u2 + l));
            float dd = 0.5f * (tu - tl - la * (u2 - l));
            lam_s[tid] = la; de_s[tid] = dd; hh_s[tid] = la * hd + mu;
        }
        __syncthreads();
        if (slot < 4) {                     // WoTp frags (lam folded)
            const int nf = slot, w4 = tid >> 6;
            u16* Wob = WoTp + (size_t)b * N_OUT * H;
            #pragma unroll
            for (int k2 = 0; k2 < 2; ++k2) {
                int kc = w4 * 2 + k2;
                const float* src = WoTf + (size_t)((nf * 8 + kc) * 64 + lane) * 8;
                int k0 = kc * 32 + (lane >> 4) * 8;
                union { u16 us[8]; uint4 v; } pk;
                #pragma unroll
                for (int j = 0; j < 8; ++j) pk.us[j] = f2bf(lam_s[k0 + j] * src[j]);
                *(uint4*)&Wob[(size_t)(nf * 8 + kc) * 512 + lane * 8] = pk.v;
            }
        } else if (tid < N_OUT) {           // slot 4: head_o + final diag radius
            float acc2 = bo_v[tid], accR = 0.f;
            #pragma unroll 4
            for (int j = 0; j < H; ++j) {
                float w = Wo[j * N_OUT + tid];
                acc2 += hh_s[j] * w;
                accR += fabsf(de_s[j] * w);
            }
            head_o[b * N_OUT + tid] = acc2;
            rad_o[b * N_OUT + tid]  = accR;   // zero-init'd; sole writer this dispatch
        }
    }
}

// ---------------------------------------------------------------------------
// final_k: pure gemm, 39 radius tiles per sample, B from WoTp bf16.
// grid (NSLOT, BSZ).
// ---------------------------------------------------------------------------
__global__ __launch_bounds__(256, 2) void final_k(
    const u16* __restrict__ err, const u16* __restrict__ WoTp,
    float* __restrict__ rad_o)
{
    __shared__ float radacc[N_OUT];
    const int slot = blockIdx.x, b = blockIdx.y, tid = threadIdx.x;
    const int wave = tid >> 6, lane = tid & 63, m = lane & 15;
    const u16* errB = err + (size_t)b * ESTRIDE * H;
    const u16* Wob  = WoTp + (size_t)b * N_OUT * H;

    if (tid < N_OUT) radacc[tid] = 0.f;
    bf16x8 bq[4][8];
    #pragma unroll
    for (int nt = 0; nt < 4; ++nt)
        #pragma unroll
        for (int kc = 0; kc < 8; ++kc)
            bq[nt][kc] = *(const bf16x8*)&Wob[(size_t)((nt * 8 + kc) * 512) + lane * 8];
    __syncthreads();

    const int NT_OUT = ESTRIDE / 256;       // 39
    for (int tau = slot; tau < NT_OUT; tau += NSLOT) {
        const int tile0 = tau * 16 + wave * 4;
        f32x4 acc[4][4];
        #pragma unroll
        for (int i = 0; i < 4; ++i)
            #pragma unroll
            for (int c = 0; c < 4; ++c) acc[i][c] = (f32x4){0.f, 0.f, 0.f, 0.f};
        #pragma unroll
        for (int kc = 0; kc < 8; ++kc) {
            bf16x8 af[4];
            #pragma unroll
            for (int rt = 0; rt < 4; ++rt)
                af[rt] = *(const bf16x8*)&errB[(size_t)((tile0 + rt) * 8 + kc) * 512 + lane * 8];
            #pragma unroll
            for (int nt = 0; nt < 4; ++nt)
                #pragma unroll
                for (int rt = 0; rt < 4; ++rt)
                    acc[rt][nt] = __builtin_amdgcn_mfma_f32_16x16x32_bf16(
                        af[rt], bq[nt][kc], acc[rt][nt], 0, 0, 0);
        }
        #pragma unroll
        for (int nt = 0; nt < 4; ++nt) {
            float s = 0.f;
            #pragma unroll
            for (int rt = 0; rt < 4; ++rt)
                #pragma unroll
                for (int r = 0; r < 4; ++r) s += fabsf(acc[rt][nt][r]);
            atomicAdd(&radacc[nt * 16 + m], s);
        }
    }
    __syncthreads();
    if (tid < N_OUT) atomicAdd(&rad_o[b * N_OUT + tid], radacc[tid]);
}

// ---------------------------------------------------------------------------
__global__ void combine_k(const float* __restrict__ head_o,
                          const float* __restrict__ rad_o,
                          float* __restrict__ out)
{
    int i = blockIdx.x * 256 + threadIdx.x;
    if (i < BSZ * N_OUT) {
        float h = head_o[i], r = rad_o[i];
        out[i]               = h - r;
        out[BSZ * N_OUT + i] = h + r;
    }
}

// ---------------------------------------------------------------------------
extern "C" void kernel_launch(void* const* d_in, const int* in_sizes, int n_in,
                              void* d_out, int out_size, void* d_ws, size_t ws_size,
                              hipStream_t stream)
{
    const float* X    = (const float*)d_in[0];
    const float* eps  = (const float*)d_in[1];
    const float* Wih  = (const float*)d_in[2];
    const float* Whh  = (const float*)d_in[3];
    const float* bih  = (const float*)d_in[4];
    const float* bhh  = (const float*)d_in[5];
    const float* Wo   = (const float*)d_in[6];
    const float* bo   = (const float*)d_in[7];
    float* out = (float*)d_out;

    char* p = (char*)d_ws;
    u16* errP      = (u16*)p;   p += (size_t)BSZ * ESTRIDE * H * 2;   // 163.6 MB
    u16* WTp       = (u16*)p;   p += (size_t)2 * BSZ * H * H * 2;     // 8 MB, parity
    u16* WoTp      = (u16*)p;   p += (size_t)BSZ * N_OUT * H * 2;     // 1 MB
    float* WhhTf   = (float*)p; p += (size_t)H * H * 4;               // frag-ordered
    float* WoTf    = (float*)p; p += (size_t)N_OUT * H * 4;
    float* hp      = (float*)p; p += (size_t)2 * BSZ * H * 4;
    // ---- zeroed region (contiguous): radT[33] + rad_o + cnt ----
    float* radT    = (float*)p; p += (size_t)33 * BSZ * H * 4;
    float* rad_o   = (float*)p; p += (size_t)BSZ * N_OUT * 4;
    int*   cnt     = (int*)p;   p += (size_t)T_STEPS * BSZ * 4;
    float* head_o  = (float*)p;

    const int nzero = (33 * BSZ * H + BSZ * N_OUT + T_STEPS * BSZ);   // floats+ints
    init_k<<<(nzero + 255) / 256, 256, 0, stream>>>(radT);
    packWf_k<<<(16 * 8 * 64) / 256, 256, 0, stream>>>(Whh, WhhTf, 16, H);
    packWf_k<<<(4 * 8 * 64) / 256, 256, 0, stream>>>(Wo, WoTf, 4, N_OUT);

    prep0_k<<<BSZ, 256, 0, stream>>>(X, eps, Wih, Whh, WhhTf, bih, bhh,
                                     hp, radT, errP, WTp);

    for (int t = 1; t < T_STEPS; ++t) {
        step_k<<<dim3(NSLOT, BSZ), 256, 0, stream>>>(
            X, eps, Wih, Whh, WhhTf, WoTf, Wo, bo, bih, bhh,
            hp, radT, errP, WTp, WoTp, head_o, rad_o, cnt, t);
    }

    final_k<<<dim3(NSLOT, BSZ), 256, 0, stream>>>(errP, WoTp, rad_o);
    combine_k<<<(BSZ * N_OUT + 255) / 256, 256, 0, stream>>>(head_o, rad_o, out);
}

// Round 12
// 3642.581 us; speedup vs baseline: 1.6239x; 1.6239x over previous
//
#include <hip/hip_runtime.h>
#include <math.h>

typedef unsigned short u16;
typedef __attribute__((ext_vector_type(8))) short bf16x8;   // MFMA A/B frag
typedef __attribute__((ext_vector_type(4))) float f32x4;    // MFMA C/D frag

#define T_STEPS 32
#define BSZ     32
#define N_IN    64
#define H       256
#define N_OUT   64
#define ESTRIDE 9984              // rows = 320*31 + 64 (final fresh block)
#define CLAMP_MIN (-2.0f)
#define CLAMP_MAX ( 2.0f)
#define GNB 32                    // gemm blocks per sample (1024 total, ~3/CU)

// Fragment-packed layout: chunk = (row>>4)*8 + (k>>5), 512 u16 per chunk,
// within-chunk elem = (((k&31)>>3)*16 + (row&15))*8 + (k&7)
// => A-frag load for (tile,kc) is base + chunk*512 + lane*8, 16B/lane coalesced.

__device__ inline u16 f2bf(float x) {                       // RTNE fp32->bf16
    unsigned u = __builtin_bit_cast(unsigned, x);
    unsigned r = u + 0x7FFFu + ((u >> 16) & 1u);
    return (u16)(r >> 16);
}

// ---------------------------------------------------------------------------
__global__ void init_k(float* __restrict__ radT) {          // zero [T][B][H]
    int i = blockIdx.x * 256 + threadIdx.x;
    radT[i] = 0.0f;
}

// ---------------------------------------------------------------------------
__global__ void transpose_k(const float* __restrict__ src, float* __restrict__ dst,
                            int R, int C)
{
    __shared__ float tile[32][33];
    int bi = blockIdx.y, bj = blockIdx.x;
    int r0 = threadIdx.x >> 5, c = threadIdx.x & 31;
    #pragma unroll
    for (int rr = 0; rr < 4; ++rr) {
        int r = r0 * 4 + rr;
        tile[r][c] = src[(bi * 32 + r) * C + bj * 32 + c];
    }
    __syncthreads();
    #pragma unroll
    for (int rr = 0; rr < 4; ++rr) {
        int r = r0 * 4 + rr;
        dst[(bj * 32 + r) * R + bi * 32 + c] = tile[c][r];
    }
}

// ---------------------------------------------------------------------------
// prep0: head_pre_0, fresh rows [0,64) frag-packed, rad[0]. grid BSZ x 256.
// ---------------------------------------------------------------------------
__global__ __launch_bounds__(256) void prep0_k(
    const float* __restrict__ X0, const float* __restrict__ eps,
    const float* __restrict__ Wih, const float* __restrict__ bih,
    const float* __restrict__ bhh,
    float* __restrict__ hp0, float* __restrict__ rad0, u16* __restrict__ err)
{
    __shared__ float hx[N_IN], rr[N_IN], rad_s[H];
    const int b = blockIdx.x, tid = threadIdx.x;
    if (tid < N_IN) {
        float x = X0[b * N_IN + tid], e = eps[b];
        float l = fmaxf(x - e, CLAMP_MIN), u = fminf(x + e, CLAMP_MAX);
        hx[tid] = 0.5f * (l + u);
        rr[tid] = 0.5f * (u - l);
    }
    rad_s[tid] = 0.f;
    __syncthreads();

    float acc = bih[tid] + bhh[tid];
    #pragma unroll 8
    for (int i = 0; i < N_IN; ++i) acc += hx[i] * Wih[i * H + tid];
    hp0[b * H + tid] = acc;

    u16* errB = err + (size_t)b * ESTRIDE * H;
    const int e = tid * 2, q = e >> 7, m = (e >> 3) & 15, j = e & 7;
    #pragma unroll
    for (int ti = 0; ti < 4; ++ti) {
        int i = ti * 16 + m;
        float rho = rr[i];
        #pragma unroll
        for (int kc = 0; kc < 8; ++kc) {
            int k = kc * 32 + q * 8 + j;
            float v0 = rho * Wih[(size_t)i * H + k];
            float v1 = rho * Wih[(size_t)i * H + k + 1];
            unsigned pk = (unsigned)f2bf(v0) | ((unsigned)f2bf(v1) << 16);
            *(unsigned*)&errB[(size_t)(ti * 8 + kc) * 512 + e] = pk;
            atomicAdd(&rad_s[k], fabsf(v0));
            atomicAdd(&rad_s[k + 1], fabsf(v1));
        }
    }
    __syncthreads();
    atomicAdd(&rad0[b * H + tid], rad_s[tid]);
}

// ---------------------------------------------------------------------------
// mid_k (t>=1): fused tanh(prev) + WT pack + diag rows + fresh rows + head GEMV.
// grid (10, BSZ), 256 thr. roles: 0..7 = WT/diag slice, 8 = head, 9 = fresh.
// ---------------------------------------------------------------------------
__global__ __launch_bounds__(256) void mid_k(
    const float* __restrict__ Xt, const float* __restrict__ eps,
    const float* __restrict__ Wih, const float* __restrict__ Whh,
    const float* __restrict__ WhhT32,
    const float* __restrict__ bih, const float* __restrict__ bhh,
    const float* __restrict__ hp_prev, const float* __restrict__ rad_prev,
    float* __restrict__ hp_new, float* __restrict__ rad_new,
    u16* __restrict__ err, u16* __restrict__ WTp, int E_old)
{
    __shared__ float lam_s[H], de_s[H], aux_s[H], hxr[N_IN];
    const int role = blockIdx.x, b = blockIdx.y, tid = threadIdx.x;

    float hd = hp_prev[b * H + tid], r = rad_prev[b * H + tid];
    float l = hd - r, u = hd + r;
    float tl = tanhf(l), tu = tanhf(u);
    float la = fminf(1.f - tl * tl, 1.f - tu * tu);
    float mu = 0.5f * (tu + tl - la * (u + l));
    float dd = 0.5f * (tu - tl - la * (u - l));
    lam_s[tid] = la;
    de_s[tid]  = dd;
    aux_s[tid] = (role == 8) ? (la * hd + mu) : 0.f;   // hh for role 8, rad acc else
    if (tid < N_IN && role >= 8) {
        float x = Xt[b * N_IN + tid], e = eps[b];
        float lo = fmaxf(x - e, CLAMP_MIN), up = fminf(x + e, CLAMP_MAX);
        hxr[tid] = (role == 8) ? 0.5f * (lo + up) : 0.5f * (up - lo);
    }
    __syncthreads();

    if (role == 8) {
        float acc = bih[tid] + bhh[tid];
        #pragma unroll 8
        for (int i = 0; i < N_IN; ++i) acc += hxr[i] * Wih[i * H + tid];
        #pragma unroll 8
        for (int jj = 0; jj < H; ++jj) acc += aux_s[jj] * Whh[jj * H + tid];
        hp_new[b * H + tid] = acc;
        return;
    }

    u16* errB = err + (size_t)b * ESTRIDE * H;
    const int e = tid * 2, q = e >> 7, m = (e >> 3) & 15, j = e & 7;

    if (role < 8) {                            // WT slice + diag rows
        const int s = role;
        const int diag_lo = E_old - H;
        u16* WTb = WTp + (size_t)b * H * H;
        #pragma unroll
        for (int ti = 0; ti < 2; ++ti) {
            int nbase = (2 * s + ti) * 16 + m;       // WT n-row
            int rsrc  = s * 32 + ti * 16 + m;        // diag source index
            float dv  = de_s[rsrc];
            #pragma unroll
            for (int kc = 0; kc < 8; ++kc) {
                int k = kc * 32 + q * 8 + j;
                float w0 = WhhT32[(size_t)nbase * H + k];
                float w1 = WhhT32[(size_t)nbase * H + k + 1];
                unsigned pw = (unsigned)f2bf(lam_s[k] * w0)
                            | ((unsigned)f2bf(lam_s[k + 1] * w1) << 16);
                *(unsigned*)&WTb[(size_t)((2 * s + ti) * 8 + kc) * 512 + e] = pw;
                float v0 = dv * Whh[(size_t)rsrc * H + k];
                float v1 = dv * Whh[(size_t)rsrc * H + k + 1];
                unsigned pv = (unsigned)f2bf(v0) | ((unsigned)f2bf(v1) << 16);
                *(unsigned*)&errB[(size_t)(((diag_lo >> 4) + 2 * s + ti) * 8 + kc) * 512 + e] = pv;
                atomicAdd(&aux_s[k], fabsf(v0));
                atomicAdd(&aux_s[k + 1], fabsf(v1));
            }
        }
    } else {                                   // role 9: fresh rows
        #pragma unroll
        for (int ti = 0; ti < 4; ++ti) {
            int i = ti * 16 + m;
            float rho = hxr[i];
            #pragma unroll
            for (int kc = 0; kc < 8; ++kc) {
                int k = kc * 32 + q * 8 + j;
                float v0 = rho * Wih[(size_t)i * H + k];
                float v1 = rho * Wih[(size_t)i * H + k + 1];
                unsigned pv = (unsigned)f2bf(v0) | ((unsigned)f2bf(v1) << 16);
                *(unsigned*)&errB[(size_t)(((E_old >> 4) + ti) * 8 + kc) * 512 + e] = pv;
                atomicAdd(&aux_s[k], fabsf(v0));
                atomicAdd(&aux_s[k + 1], fabsf(v1));
            }
        }
    }
    __syncthreads();
    atomicAdd(&rad_new[b * H + tid], aux_s[tid]);
}

// ---------------------------------------------------------------------------
// Main MFMA GEMM, in place, frag-packed, occupancy-tuned:
//   err[0..ntiles*64) <- err @ WT^T, grid (GNB, BSZ); block strides tiles.
// B frags re-read per tile from global WTp (L2-hot, frees 128 VGPRs).
// tbuf is 8 KB (rt-by-rt transform). 3 blocks/CU target. Idle blocks exit.
// rad_new[b,h] += sum_rows |C|.
// ---------------------------------------------------------------------------
__global__ __launch_bounds__(256, 3) void gemm_k(
    u16* __restrict__ err, const u16* __restrict__ WTp,
    float* __restrict__ rad_new, int ntiles)
{
    __shared__ u16 tbuf[4][1024];          // 8 KB: per-wave 2 chunks
    __shared__ float rad_s[H];
    const int slot = blockIdx.x, b = blockIdx.y, tid = threadIdx.x;
    if (slot >= ntiles) return;            // idle block
    const int wave = tid >> 6, lane = tid & 63;
    const int m = lane & 15, q = lane >> 4;
    u16* errB = err + (size_t)b * ESTRIDE * H;
    const u16* WTb = WTp + (size_t)b * H * H;

    rad_s[tid] = 0.f;
    __syncthreads();   // rad_s visible

    for (int tile = slot; tile < ntiles; tile += GNB) {
        f32x4 acc[4][4];
        #pragma unroll
        for (int i = 0; i < 4; ++i)
            #pragma unroll
            for (int c = 0; c < 4; ++c) acc[i][c] = (f32x4){0.f, 0.f, 0.f, 0.f};

        #pragma unroll
        for (int kc = 0; kc < 8; ++kc) {
            bf16x8 af[4], bf[4];
            #pragma unroll
            for (int rt = 0; rt < 4; ++rt)
                af[rt] = *(const bf16x8*)&errB[(size_t)((tile * 4 + rt) * 8 + kc) * 512 + lane * 8];
            #pragma unroll
            for (int nt = 0; nt < 4; ++nt)
                bf[nt] = *(const bf16x8*)&WTb[(size_t)((wave * 4 + nt) * 8 + kc) * 512 + lane * 8];
            #pragma unroll
            for (int nt = 0; nt < 4; ++nt)
                #pragma unroll
                for (int rt = 0; rt < 4; ++rt)
                    acc[rt][nt] = __builtin_amdgcn_mfma_f32_16x16x32_bf16(
                        af[rt], bf[nt], acc[rt][nt], 0, 0, 0);
        }
        __syncthreads();   // every wave consumed this tile's A before stores

        // transform C (col=lane&15, row=q*4+reg) -> A-frag layout, rt-by-rt
        // (same index mapping as the verified 32 KB version, minus rt*1024)
        float sacc[4] = {0.f, 0.f, 0.f, 0.f};
        u16* W_ = tbuf[wave];
        #pragma unroll
        for (int rt = 0; rt < 4; ++rt) {
            #pragma unroll
            for (int nt = 0; nt < 4; ++nt) {
                int c32 = (nt & 1) * 16 + m;   // k within 32-chunk
                int q_a = c32 >> 3, jj = c32 & 7, kcl = nt >> 1;
                #pragma unroll
                for (int r = 0; r < 4; ++r) {
                    float v = acc[rt][nt][r];
                    sacc[nt] += fabsf(v);
                    W_[kcl * 512 + (q_a * 16 + q * 4 + r) * 8 + jj] = f2bf(v);
                }
            }
            #pragma unroll
            for (int kcl = 0; kcl < 2; ++kcl) {
                uint4 v = *(uint4*)&W_[kcl * 512 + lane * 8];
                *(uint4*)&errB[(size_t)((tile * 4 + rt) * 8 + wave * 2 + kcl) * 512 + lane * 8] = v;
            }
        }
        #pragma unroll
        for (int nt = 0; nt < 4; ++nt)
            atomicAdd(&rad_s[wave * 64 + nt * 16 + m], sacc[nt]);
    }
    __syncthreads();
    atomicAdd(&rad_new[b * H + tid], rad_s[tid]);
}

// ---------------------------------------------------------------------------
__global__ __launch_bounds__(256) void tanh_final_k(
    const float* __restrict__ hp, const float* __restrict__ rad,
    float* __restrict__ lam, float* __restrict__ de, float* __restrict__ head_h)
{
    const int b = blockIdx.x, h = threadIdx.x;
    float hd = hp[b * H + h], r = rad[b * H + h];
    float l = hd - r, u = hd + r;
    float tl = tanhf(l), tu = tanhf(u);
    float la = fminf(1.f - tl * tl, 1.f - tu * tu);
    float mu = 0.5f * (tu + tl - la * (u + l));
    float dd = 0.5f * (tu - tl - la * (u - l));
    lam[b * H + h] = la;
    de[b * H + h]  = dd;
    head_h[b * H + h] = la * hd + mu;
}

// ---------------------------------------------------------------------------
// pack WoT frag-packed, lam folded. grid BSZ x 256.
// ---------------------------------------------------------------------------
__global__ __launch_bounds__(256) void packWoT_k(
    const float* __restrict__ WoT32, const float* __restrict__ lam,
    u16* __restrict__ WoTp)
{
    const int b = blockIdx.x, tid = threadIdx.x;
    __shared__ float lam_s[H];
    lam_s[tid] = lam[b * H + tid];
    __syncthreads();
    u16* dst = WoTp + (size_t)b * N_OUT * H;
    const int e = tid * 2, q = e >> 7, m = (e >> 3) & 15, j = e & 7;
    #pragma unroll
    for (int nt = 0; nt < 4; ++nt) {
        int n = nt * 16 + m;
        #pragma unroll
        for (int kc = 0; kc < 8; ++kc) {
            int k = kc * 32 + q * 8 + j;
            unsigned pw = (unsigned)f2bf(lam_s[k] * WoT32[(size_t)n * H + k])
                        | ((unsigned)f2bf(lam_s[k + 1] * WoT32[(size_t)n * H + k + 1]) << 16);
            *(unsigned*)&dst[(size_t)(nt * 8 + kc) * 512 + e] = pw;
        }
    }
}

// ---------------------------------------------------------------------------
__global__ void head_out_k(
    const float* __restrict__ head_h, const float* __restrict__ de,
    const float* __restrict__ Wo, const float* __restrict__ bo,
    float* __restrict__ head_out, float* __restrict__ rad_out)
{
    const int b = blockIdx.x, o = threadIdx.x;
    float acc = bo[o], accR = 0.f;
    #pragma unroll 4
    for (int j = 0; j < H; ++j) {
        float w = Wo[j * N_OUT + o];
        acc  += head_h[b * H + j] * w;
        accR += fabsf(de[b * H + j] * w);
    }
    head_out[b * N_OUT + o] = acc;
    rad_out[b * N_OUT + o]  = accR;
}

// ---------------------------------------------------------------------------
// final radius: rad_out += sum_rows |err @ WoTp^T| over all ESTRIDE rows.
// Block 256 rows x 64 cols, 4 waves (wave 64x64). grid (ESTRIDE/256, BSZ).
// ---------------------------------------------------------------------------
__global__ __launch_bounds__(256) void gemm_out_k(
    const u16* __restrict__ err, const u16* __restrict__ WoTp,
    float* __restrict__ rad_out)
{
    __shared__ float rad_s[N_OUT];
    const int b = blockIdx.y, row0 = blockIdx.x * 256, tid = threadIdx.x;
    const int wave = tid >> 6, lane = tid & 63;
    const int m = lane & 15;
    const u16* errB = err + (size_t)b * ESTRIDE * H;
    const u16* Wb   = WoTp + (size_t)b * N_OUT * H;

    if (tid < N_OUT) rad_s[tid] = 0.f;
    __syncthreads();

    f32x4 acc[4][4];
    #pragma unroll
    for (int i = 0; i < 4; ++i)
        #pragma unroll
        for (int c = 0; c < 4; ++c) acc[i][c] = (f32x4){0.f, 0.f, 0.f, 0.f};

    const int tile0 = (row0 >> 4) + wave * 4;
    #pragma unroll
    for (int kc = 0; kc < 8; ++kc) {
        bf16x8 af[4], bf[4];
        #pragma unroll
        for (int rt = 0; rt < 4; ++rt)
            af[rt] = *(const bf16x8*)&errB[(size_t)((tile0 + rt) * 8 + kc) * 512 + lane * 8];
        #pragma unroll
        for (int nt = 0; nt < 4; ++nt)
            bf[nt] = *(const bf16x8*)&Wb[(size_t)(nt * 8 + kc) * 512 + lane * 8];
        #pragma unroll
        for (int nt = 0; nt < 4; ++nt)
            #pragma unroll
            for (int rt = 0; rt < 4; ++rt)
                acc[rt][nt] = __builtin_amdgcn_mfma_f32_16x16x32_bf16(
                    af[rt], bf[nt], acc[rt][nt], 0, 0, 0);
    }
    #pragma unroll
    for (int nt = 0; nt < 4; ++nt) {
        float s = 0.f;
        #pragma unroll
        for (int rt = 0; rt < 4; ++rt)
            #pragma unroll
            for (int r = 0; r < 4; ++r) s += fabsf(acc[nt < 0 ? 0 : rt][nt][r]);
        atomicAdd(&rad_s[nt * 16 + m], s);
    }
    __syncthreads();
    if (tid < N_OUT) atomicAdd(&rad_out[b * N_OUT + tid], rad_s[tid]);
}

// ---------------------------------------------------------------------------
__global__ void combine_k(const float* __restrict__ head_out,
                          const float* __restrict__ rad_out,
                          float* __restrict__ out)
{
    int i = blockIdx.x * 256 + threadIdx.x;
    if (i < BSZ * N_OUT) {
        float h = head_out[i], r = rad_out[i];
        out[i]               = h - r;
        out[BSZ * N_OUT + i] = h + r;
    }
}

// ---------------------------------------------------------------------------
extern "C" void kernel_launch(void* const* d_in, const int* in_sizes, int n_in,
                              void* d_out, int out_size, void* d_ws, size_t ws_size,
                              hipStream_t stream)
{
    const float* X    = (const float*)d_in[0];
    const float* eps  = (const float*)d_in[1];
    const float* Wih  = (const float*)d_in[2];
    const float* Whh  = (const float*)d_in[3];
    const float* bih  = (const float*)d_in[4];
    const float* bhh  = (const float*)d_in[5];
    const float* Wo   = (const float*)d_in[6];
    const float* bo   = (const float*)d_in[7];
    float* out = (float*)d_out;

    char* p = (char*)d_ws;
    u16* errP      = (u16*)p;   p += (size_t)BSZ * ESTRIDE * H * 2;   // 163.6 MB
    u16* WTp       = (u16*)p;   p += (size_t)BSZ * H * H * 2;         // 4 MB
    u16* WoTp      = (u16*)p;   p += (size_t)BSZ * N_OUT * H * 2;     // 1 MB
    float* WhhT32  = (float*)p; p += (size_t)H * H * 4;
    float* WoT32   = (float*)p; p += (size_t)N_OUT * H * 4;
    float* hp      = (float*)p; p += (size_t)2 * BSZ * H * 4;
    float* radT    = (float*)p; p += (size_t)T_STEPS * BSZ * H * 4;   // zeroed
    float* lam     = (float*)p; p += (size_t)BSZ * H * 4;
    float* de      = (float*)p; p += (size_t)BSZ * H * 4;
    float* head_h  = (float*)p; p += (size_t)BSZ * H * 4;
    float* head_o  = (float*)p; p += (size_t)BSZ * N_OUT * 4;
    float* rad_o   = (float*)p;

    init_k<<<(T_STEPS * BSZ * H) / 256, 256, 0, stream>>>(radT);
    transpose_k<<<dim3(H / 32, H / 32), 256, 0, stream>>>(Whh, WhhT32, H, H);
    transpose_k<<<dim3(N_OUT / 32, H / 32), 256, 0, stream>>>(Wo, WoT32, H, N_OUT);

    prep0_k<<<BSZ, 256, 0, stream>>>(X, eps, Wih, bih, bhh, hp, radT, errP);

    for (int t = 1; t < T_STEPS; ++t) {
        int E_old = t * (N_IN + H);
        int ntiles = (E_old - H) / 64;   // 5t-4
        const float* hp_prev  = hp + (size_t)((t - 1) & 1) * BSZ * H;
        float*       hp_new   = hp + (size_t)(t & 1) * BSZ * H;
        const float* rad_prev = radT + (size_t)(t - 1) * BSZ * H;
        float*       rad_new  = radT + (size_t)t * BSZ * H;
        mid_k<<<dim3(10, BSZ), 256, 0, stream>>>(
            X + (size_t)t * BSZ * N_IN, eps, Wih, Whh, WhhT32,
            bih, bhh, hp_prev, rad_prev, hp_new, rad_new, errP, WTp, E_old);
        gemm_k<<<dim3(GNB, BSZ), 256, 0, stream>>>(
            errP, WTp, rad_new, ntiles);
    }

    tanh_final_k<<<BSZ, 256, 0, stream>>>(
        hp + (size_t)((T_STEPS - 1) & 1) * BSZ * H,
        radT + (size_t)(T_STEPS - 1) * BSZ * H, lam, de, head_h);
    packWoT_k<<<BSZ, 256, 0, stream>>>(WoT32, lam, WoTp);
    head_out_k<<<BSZ, 64, 0, stream>>>(head_h, de, Wo, bo, head_o, rad_o);
    gemm_out_k<<<dim3(ESTRIDE / 256, BSZ), 256, 0, stream>>>(errP, WoTp, rad_o);
    combine_k<<<(BSZ * N_OUT + 255) / 256, 256, 0, stream>>>(head_o, rad_o, out);
}